// Round 7
// baseline (889.074 us; speedup 1.0000x reference)
//
#include <hip/hip_runtime.h>

// Problem constants: B=16, T=4096, D=256, K=1024
#define N_TOK 65536
#define DIM   256
#define KCODE 1024

#define NTHREADS 256
#define TM 128          // tokens per block
#define TN 128          // codes per block
#define BK 32           // bf16 k-elems per stage
#define NCHUNK 8        // code chunks (1024/128)
#define NSTAGE 8        // R7: 8 fat stages (3 products each) over K=256
#define OTM 128         // tokens per output block

// fp32 gap below which the top-2 go to fp64 refinement (bf16x3 dot err ~1e-2 bound)
#define REFINE_EPS 0.125f
// fp64 gap below which the reference's fp32 pipeline likely collapsed the two
// distances onto the same fp32 grid point -> first-occurrence -> LOWER index.
#define TIE_THETA 1.0e-4

// ws layout (floats):
//   [0]                    loss accum
//   [16 .. 16+1024)        c_sq (numpy-pairwise-exact)
//   [2048 .. +65536)       (unused; kept for layout stability)
//   [67584 .. +8*4*65536)  pairs (float4, chunk-major: pairs[c*N_TOK + t])
//   [then]                 cb packed tile-major bf16 hi/lo (1 MB)
#define WS_CSQ_OFF   16
#define WS_IDX_OFF   2048
#define WS_PAIRS_OFF (WS_IDX_OFF + N_TOK)
#define WS_CBPK_OFF  (WS_PAIRS_OFF + N_TOK * NCHUNK * 4)

typedef float f32x4  __attribute__((ext_vector_type(4)));
typedef short bf16x8 __attribute__((ext_vector_type(8)));
typedef short s16x8  __attribute__((ext_vector_type(8)));

// numpy-pairwise-exact row sum-of-squares for [rows, 256] fp32 (codebook).
// Also zeroes the loss accumulator (folded zero_loss launch).
__global__ void rowsq_np_kernel(const float* __restrict__ m,
                                float* __restrict__ out,
                                float* __restrict__ loss_ws, int rows) {
#pragma clang fp contract(off)
    if (blockIdx.x == 0 && threadIdx.x == 0) loss_ws[0] = 0.0f;
    int row = blockIdx.x * 16 + (threadIdx.x >> 4);
    int l   = threadIdx.x & 15;
    if (row >= rows) return;
    int h = l >> 3;
    int j = l & 7;
    const float* p = m + (size_t)row * DIM + h * 128 + j;
    float v = p[0];
    float r = v * v;
#pragma unroll
    for (int i = 1; i < 16; ++i) {
        float w  = p[i * 8];
        float w2 = w * w;
        r = r + w2;
    }
    float t = r + __shfl_xor(r, 1);
    t = t + __shfl_xor(t, 2);
    t = t + __shfl_xor(t, 4);
    t = t + __shfl_xor(t, 8);
    if (l == 0) out[row] = t;
}

// Insert (d, idx) into a sorted top-2 with lower-index tie-break.
__device__ __forceinline__ void ins2(float d, int idx,
                                     float& d1, int& i1, float& d2, int& i2) {
    if (d < d1 || (d == d1 && idx < i1)) {
        d2 = d1; i2 = i1; d1 = d; i1 = idx;
    } else if ((d < d2 || (d == d2 && idx < i2)) && idx != i1) {
        d2 = d; i2 = idx;
    }
}

// RNE fp32 -> bf16 split: v = hi + lo with lo capturing the residual.
__device__ __forceinline__ void f2bf_split(float v, short& hi, short& lo) {
    unsigned u = __float_as_uint(v);
    unsigned r = (u + 0x7fffu + ((u >> 16) & 1u)) >> 16;
    hi = (short)r;
    float hf = __uint_as_float(r << 16);
    float lf = v - hf;
    unsigned u2 = __float_as_uint(lf);
    unsigned r2 = (u2 + 0x7fffu + ((u2 >> 16) & 1u)) >> 16;
    lo = (short)r2;
}

// Tile-major pack (verbatim from the verified R2 kernel). Output: chunk
// c = (g*16 + part*8 + kc), each chunk 128 rows x 32 shorts (8 KB
// contiguous). Within a row, slot s (8 shorts) holds k-octet s^((r>>1)&3)
// of k-range [kc*32, kc*32+32) — the LDS bank swizzle baked into global
// layout so global_load_lds stages linearly on BOTH sides (rule #21) and
// ds_read uses slot = q ^ ((r>>1)&3).
__global__ void pack_tiles_kernel(const float* __restrict__ src,
                                  unsigned short* __restrict__ dst,
                                  int total) {       // total = rows * 32
    int tid = blockIdx.x * blockDim.x + threadIdx.x;
    if (tid >= total) return;
    int s   = tid & 3;
    int r   = (tid >> 2) & 127;
    int kc  = (tid >> 9) & 7;
    int g   = tid >> 12;
    int oct = s ^ ((r >> 1) & 3);

    const float4* xr = reinterpret_cast<const float4*>(
        src + ((size_t)(g * 128 + r)) * DIM + kc * 32 + oct * 8);
    float4 v0 = xr[0];
    float4 v1 = xr[1];

    float f[8] = {v0.x, v0.y, v0.z, v0.w, v1.x, v1.y, v1.z, v1.w};
    s16x8 hv, lv;
#pragma unroll
    for (int i = 0; i < 8; ++i) {
        short h, l;
        f2bf_split(f[i], h, l);
        hv[i] = h; lv[i] = l;
    }
    size_t base_hi = (((size_t)(g * 16 + kc) * 128 + r) << 5) + s * 8;
    size_t base_lo = (((size_t)(g * 16 + 8 + kc) * 128 + r) << 5) + s * 8;
    *reinterpret_cast<s16x8*>(dst + base_hi) = hv;
    *reinterpret_cast<s16x8*>(dst + base_lo) = lv;
}

// Async global -> LDS, 16 B per lane; LDS dest = uniform base + lane*16.
__device__ __forceinline__ void gload_lds16(const unsigned short* g, unsigned short* lds) {
    __builtin_amdgcn_global_load_lds(
        (const __attribute__((address_space(1))) unsigned int*)g,
        (__attribute__((address_space(3))) unsigned int*)lds, 16, 0, 0);
}

// MFMA distance + top-2. dist' = c_sq - 2*(x.c); ||x||^2 dropped (cancels).
// dot = hi*hi + hi*lo + lo*hi, all three products computed per k-slice.
//
// R7 restructure: the stage-count law (R0-R6: time tracks barrier-separated
// stage count, not sync mechanism/traffic/occupancy) says the fix is FATTER
// stages, not better sync. Each stage now loads A-hi, A-lo, B-hi, B-lo for
// one 32-k slice (4 chunks = 32 KB) and runs all 3 products = 48 MFMAs/wave
// (~1160 cyc) per stage — compute now exceeds the exposed latency+sync cost
// it must hide. 24 stages -> 8; hi-parts staged once (384 -> 256 KB/block).
// Numerics: same 24 fp32-accumulated terms per acc, reordered kc-major
// (reorder shifts d by ~1e-4, 100x inside REFINE_EPS margin; refine/tie
// machinery is order-independent). Double-buffered 64 KB LDS, R2's proven
// one-barrier-per-stage prefetch, launch_bounds(256,2) (no spill possible).
__launch_bounds__(NTHREADS, 2)
__global__ void vq_main_kernel(const unsigned short* __restrict__ xpk,
                               const unsigned short* __restrict__ cbpk,
                               const float* __restrict__ csq,
                               float4* __restrict__ pairs) {
    // 2 x [ Ah | Al | Bh | Bl ] x 4096 shorts = 64 KB + 4 KB epilogue
    __shared__ __align__(16) unsigned short shbuf[2][4 * 4096];
    __shared__ float4 pairs_sh[TM][2];

    const int tid  = threadIdx.x;
    const int w    = tid >> 6;       // wave 0..3
    const int wy   = w >> 1;         // wave row (token dim)
    const int wx   = w & 1;          // wave col (code dim)
    const int lane = tid & 63;
    const int lm   = lane & 15;
    const int q    = lane >> 4;

    // XCD-grouped swizzle (bijective): the 8 sibling chunk-blocks of one
    // token group are adjacent in dispatch -> x slabs L2-shared.
    const int bx     = blockIdx.x;
    const int jj     = bx >> 3;
    const int grp    = (bx & 7) + ((jj >> 3) << 3);
    const int cchunk = jj & 7;
    const int tok0   = grp * TM;
    const int code0  = cchunk * TN;

    float cs_reg[4];
#pragma unroll
    for (int ni = 0; ni < 4; ++ni)
        cs_reg[ni] = csq[code0 + wx * 64 + ni * 16 + lm];

    f32x4 acc[4][4];
#pragma unroll
    for (int mi = 0; mi < 4; ++mi)
#pragma unroll
        for (int ni = 0; ni < 4; ++ni)
            acc[mi][ni] = (f32x4){0.f, 0.f, 0.f, 0.f};

    // Tile-local fragment offsets (shorts): row r, k-octet q at swizzled
    // slot (q ^ ((r>>1)&3)). Tiles are 4096 shorts each.
    int offA[4], offB[4];
#pragma unroll
    for (int mi = 0; mi < 4; ++mi) {
        int r = wy * 64 + mi * 16 + lm;
        offA[mi] = r * BK + ((q ^ ((r >> 1) & 3)) * 8);
    }
#pragma unroll
    for (int ni = 0; ni < 4; ++ni) {
        int r = wx * 64 + ni * 16 + lm;
        offB[ni] = r * BK + ((q ^ ((r >> 1) & 3)) * 8);
    }

    // Stage kc (0..7): 4 chunks {A-hi, A-lo, B-hi, B-lo} of 32-k slice kc.
    // Chunk ids: A-hi = grp*16+kc, A-lo = grp*16+8+kc (same pattern for B).
    const int lsrc = w * 1024 + lane * 8;   // per-lane source offset (shorts)
    auto stage = [&](int p, int kc) {
        const unsigned short* gah = xpk  + (((size_t)(grp    * 16 +     kc)) << 12) + lsrc;
        const unsigned short* gal = xpk  + (((size_t)(grp    * 16 + 8 + kc)) << 12) + lsrc;
        const unsigned short* gbh = cbpk + (((size_t)(cchunk * 16 +     kc)) << 12) + lsrc;
        const unsigned short* gbl = cbpk + (((size_t)(cchunk * 16 + 8 + kc)) << 12) + lsrc;
        unsigned short* base = &shbuf[p][w * 1024];
        gload_lds16(gah,       base);
        gload_lds16(gah + 512, base + 512);
        gload_lds16(gal,       base + 4096);
        gload_lds16(gal + 512, base + 4096 + 512);
        gload_lds16(gbh,       base + 8192);
        gload_lds16(gbh + 512, base + 8192 + 512);
        gload_lds16(gbl,       base + 12288);
        gload_lds16(gbl + 512, base + 12288 + 512);
    };

    // Prologue: fill buffer 0 with stage 0, drain.
    stage(0, 0);
    __syncthreads();

    int p = 0;
#pragma unroll 1
    for (int kc = 0; kc < NSTAGE; ++kc) {
        if (kc < NSTAGE - 1) stage(p ^ 1, kc + 1);   // prefetch overlaps compute

        const unsigned short* buf = &shbuf[p][0];
        bf16x8 ah[4], al[4], bh[4], bl[4];
#pragma unroll
        for (int mi = 0; mi < 4; ++mi) {
            ah[mi] = *reinterpret_cast<const bf16x8*>(buf + offA[mi]);
            al[mi] = *reinterpret_cast<const bf16x8*>(buf + 4096 + offA[mi]);
        }
#pragma unroll
        for (int ni = 0; ni < 4; ++ni) {
            bh[ni] = *reinterpret_cast<const bf16x8*>(buf + 8192 + offB[ni]);
            bl[ni] = *reinterpret_cast<const bf16x8*>(buf + 12288 + offB[ni]);
        }

        __builtin_amdgcn_s_setprio(1);
#pragma unroll
        for (int mi = 0; mi < 4; ++mi)
#pragma unroll
            for (int ni = 0; ni < 4; ++ni)
                acc[mi][ni] = __builtin_amdgcn_mfma_f32_16x16x32_bf16(
                    ah[mi], bh[ni], acc[mi][ni], 0, 0, 0);
#pragma unroll
        for (int mi = 0; mi < 4; ++mi)
#pragma unroll
            for (int ni = 0; ni < 4; ++ni)
                acc[mi][ni] = __builtin_amdgcn_mfma_f32_16x16x32_bf16(
                    ah[mi], bl[ni], acc[mi][ni], 0, 0, 0);
#pragma unroll
        for (int mi = 0; mi < 4; ++mi)
#pragma unroll
            for (int ni = 0; ni < 4; ++ni)
                acc[mi][ni] = __builtin_amdgcn_mfma_f32_16x16x32_bf16(
                    al[mi], bh[ni], acc[mi][ni], 0, 0, 0);
        __builtin_amdgcn_s_setprio(0);

        __syncthreads();   // drains vmcnt (prefetch landed) + lgkm (reads done)
        p ^= 1;
    }

    // Extraction: C/D layout row=(q*4+reg), col=lm per 16x16 tile (verified R6).
#pragma unroll
    for (int mi = 0; mi < 4; ++mi) {
#pragma unroll
        for (int r = 0; r < 4; ++r) {
            int row_local = wy * 64 + mi * 16 + q * 4 + r;
            float l1 = 3.4e38f, l2 = 3.4e38f;
            int   j1 = 0x7fffffff, j2 = 0x7fffffff;
#pragma unroll
            for (int ni = 0; ni < 4; ++ni) {
                float d = cs_reg[ni] - 2.0f * acc[mi][ni][r];
                ins2(d, code0 + wx * 64 + ni * 16 + lm, l1, j1, l2, j2);
            }
#pragma unroll
            for (int m = 1; m < 16; m <<= 1) {
                float o1 = __shfl_xor(l1, m);
                int   p1 = __shfl_xor(j1, m);
                float o2 = __shfl_xor(l2, m);
                int   p2 = __shfl_xor(j2, m);
                ins2(o1, p1, l1, j1, l2, j2);
                ins2(o2, p2, l1, j1, l2, j2);
            }
            if (lm == 0) {
                float4 pr;
                pr.x = l1; pr.y = l2;
                pr.z = __int_as_float(j1); pr.w = __int_as_float(j2);
                pairs_sh[row_local][wx] = pr;
            }
        }
    }
    __syncthreads();
    if (tid < TM) {
        float4 pa = pairs_sh[tid][0];
        float4 pb = pairs_sh[tid][1];
        float d1 = pa.x, d2 = pa.y;
        int   i1 = __float_as_int(pa.z), i2 = __float_as_int(pa.w);
        ins2(pb.x, __float_as_int(pb.z), d1, i1, d2, i2);
        ins2(pb.y, __float_as_int(pb.w), d1, i1, d2, i2);
        float4 pr;
        pr.x = d1; pr.y = d2;
        pr.z = __int_as_float(i1); pr.w = __int_as_float(i2);
        // chunk-major: contiguous 16B stores across tid
        pairs[(size_t)cchunk * N_TOK + tok0 + tid] = pr;
    }
}

// Fused merge + refine + output. Phase 1: 128 threads merge the 8 chunk
// top-2 pairs (ascending chunk order) and fp64-refine near-ties. Phase 2:
// all 256 threads write quantized rows + indices + loss partials.
__launch_bounds__(256)
__global__ void merge_output_kernel(const float* __restrict__ x,
                                    const float* __restrict__ cb,
                                    const float4* __restrict__ pairs,
                                    float* __restrict__ out_q,
                                    float* __restrict__ out_idx,
                                    float* __restrict__ loss_ws) {
    __shared__ int   sh_idx[OTM];
    __shared__ float wsum[4];
    const int tid  = threadIdx.x;
    const int tok0 = blockIdx.x * OTM;

    if (tid < OTM) {
        const int t = tok0 + tid;
        float4 p0 = pairs[t];
        float d1 = p0.x, d2 = p0.y;
        int   i1 = __float_as_int(p0.z), i2 = __float_as_int(p0.w);
#pragma unroll
        for (int c = 1; c < NCHUNK; ++c) {
            float4 p = pairs[(size_t)c * N_TOK + t];
            ins2(p.x, __float_as_int(p.z), d1, i1, d2, i2);
            ins2(p.y, __float_as_int(p.w), d1, i1, d2, i2);
        }

        int pick = i1;
        if (d2 - d1 < REFINE_EPS) {
            const float* xr = x + (size_t)t * DIM;
            const float* c1 = cb + (size_t)i1 * DIM;
            const float* c2 = cb + (size_t)i2 * DIM;
            double sA = 0.0, dA = 0.0, sB = 0.0, dB = 0.0;
            for (int k = 0; k < DIM; ++k) {
                double xv = (double)xr[k];
                double a  = (double)c1[k];
                double b  = (double)c2[k];
                sA += a * a; dA += xv * a;
                sB += b * b; dB += xv * b;
            }
            double DA  = sA - 2.0 * dA;
            double DB  = sB - 2.0 * dB;
            double gap = DB - DA;
            if (gap > TIE_THETA)       pick = i1;
            else if (gap < -TIE_THETA) pick = i2;
            else                       pick = (i1 < i2) ? i1 : i2;
        }
        sh_idx[tid] = pick;
        out_idx[t]  = (float)pick;
    }
    __syncthreads();

    float lsum = 0.0f;
    for (int t = 0; t < OTM; ++t) {
        int code = sh_idx[t];
        float qv = cb[(size_t)code * DIM + tid];
        float xv = x[(size_t)(tok0 + t) * DIM + tid];
        out_q[(size_t)(tok0 + t) * DIM + tid] = xv + (qv - xv);
        float df = xv - qv;
        lsum = fmaf(df, df, lsum);
    }

#pragma unroll
    for (int off = 1; off < 64; off <<= 1) lsum += __shfl_xor(lsum, off);
    if ((tid & 63) == 0) wsum[tid >> 6] = lsum;
    __syncthreads();
    if (tid == 0) atomicAdd(loss_ws, (wsum[0] + wsum[1]) + (wsum[2] + wsum[3]));
}

__global__ void finalize_kernel(const float* ws, float* out_loss) {
    if (threadIdx.x == 0) out_loss[0] = ws[0] * (1.0f / 16777216.0f); // COMMITMENT * mean
}

extern "C" void kernel_launch(void* const* d_in, const int* in_sizes, int n_in,
                              void* d_out, int out_size, void* d_ws, size_t ws_size,
                              hipStream_t stream) {
    const float* x  = (const float*)d_in[0];   // [16,4096,256] fp32
    const float* cb = (const float*)d_in[1];   // [1024,256] fp32

    float* out      = (float*)d_out;
    float* out_q    = out;
    float* out_idx  = out + (size_t)N_TOK * DIM;
    float* out_loss = out_idx + N_TOK;

    float*  ws    = (float*)d_ws;
    float*  csq   = ws + WS_CSQ_OFF;
    float4* pairs = (float4*)(ws + WS_PAIRS_OFF);
    unsigned short* cbpk = (unsigned short*)(ws + WS_CBPK_OFF);
    // x packed bf16 hi/lo lives in the out_q region (64 MB, overwritten later)
    unsigned short* xpk  = (unsigned short*)out_q;

    rowsq_np_kernel<<<KCODE / 16, 256, 0, stream>>>(cb, csq, ws, KCODE);
    // x: 65536 rows * 32 threads/row; cb: 1024 rows * 32 threads/row
    pack_tiles_kernel<<<(N_TOK * 32) / 256, 256, 0, stream>>>(x, xpk, N_TOK * 32);
    pack_tiles_kernel<<<(KCODE * 32) / 256, 256, 0, stream>>>(cb, cbpk, KCODE * 32);
    vq_main_kernel<<<(N_TOK / TM) * NCHUNK, NTHREADS, 0, stream>>>(xpk, cbpk, csq, pairs);
    merge_output_kernel<<<N_TOK / OTM, 256, 0, stream>>>(x, cb, pairs, out_q, out_idx, ws);
    finalize_kernel<<<1, 64, 0, stream>>>(ws, out_loss);
}

// Round 8
// 793.890 us; speedup vs baseline: 1.1199x; 1.1199x over previous
//
#include <hip/hip_runtime.h>

// Problem constants: B=16, T=4096, D=256, K=1024
#define N_TOK 65536
#define DIM   256
#define KCODE 1024

#define NTHREADS 256
#define TM 128          // tokens per block
#define TN 128          // codes per block
#define BK 32           // bf16 k-elems per stage
#define NCHUNK 8        // code chunks (1024/128)
#define NSTAGE 24       // 3 segments x 8 k-chunks of 32
#define OTM 128         // tokens per output block

// fp32 gap below which the top-2 go to fp64 refinement (bf16x3 dot err ~1e-2 bound)
#define REFINE_EPS 0.125f
// fp64 gap below which the reference's fp32 pipeline likely collapsed the two
// distances onto the same fp32 grid point -> first-occurrence -> LOWER index.
#define TIE_THETA 1.0e-4

// ws layout (floats):
//   [0]                    loss accum
//   [16 .. 16+1024)        c_sq (numpy-pairwise-exact)
//   [2048 .. +65536)       (unused; kept for layout stability)
//   [67584 .. +8*4*65536)  pairs (float4, chunk-major: pairs[c*N_TOK + t])
//   [then]                 cb packed tile-major bf16 hi/lo, UNSWIZZLED (1 MB)
#define WS_CSQ_OFF   16
#define WS_IDX_OFF   2048
#define WS_PAIRS_OFF (WS_IDX_OFF + N_TOK)
#define WS_CBPK_OFF  (WS_PAIRS_OFF + N_TOK * NCHUNK * 4)

typedef float f32x4  __attribute__((ext_vector_type(4)));
typedef short bf16x8 __attribute__((ext_vector_type(8)));
typedef short s16x8  __attribute__((ext_vector_type(8)));

// numpy-pairwise-exact row sum-of-squares for [rows, 256] fp32 (codebook).
// Also zeroes the loss accumulator (folded zero_loss launch).
__global__ void rowsq_np_kernel(const float* __restrict__ m,
                                float* __restrict__ out,
                                float* __restrict__ loss_ws, int rows) {
#pragma clang fp contract(off)
    if (blockIdx.x == 0 && threadIdx.x == 0) loss_ws[0] = 0.0f;
    int row = blockIdx.x * 16 + (threadIdx.x >> 4);
    int l   = threadIdx.x & 15;
    if (row >= rows) return;
    int h = l >> 3;
    int j = l & 7;
    const float* p = m + (size_t)row * DIM + h * 128 + j;
    float v = p[0];
    float r = v * v;
#pragma unroll
    for (int i = 1; i < 16; ++i) {
        float w  = p[i * 8];
        float w2 = w * w;
        r = r + w2;
    }
    float t = r + __shfl_xor(r, 1);
    t = t + __shfl_xor(t, 2);
    t = t + __shfl_xor(t, 4);
    t = t + __shfl_xor(t, 8);
    if (l == 0) out[row] = t;
}

// Insert (d, idx) into a sorted top-2 with lower-index tie-break.
__device__ __forceinline__ void ins2(float d, int idx,
                                     float& d1, int& i1, float& d2, int& i2) {
    if (d < d1 || (d == d1 && idx < i1)) {
        d2 = d1; i2 = i1; d1 = d; i1 = idx;
    } else if ((d < d2 || (d == d2 && idx < i2)) && idx != i1) {
        d2 = d; i2 = idx;
    }
}

// RNE fp32 -> bf16 split: v = hi + lo with lo capturing the residual.
__device__ __forceinline__ void f2bf_split(float v, short& hi, short& lo) {
    unsigned u = __float_as_uint(v);
    unsigned r = (u + 0x7fffu + ((u >> 16) & 1u)) >> 16;
    hi = (short)r;
    float hf = __uint_as_float(r << 16);
    float lf = v - hf;
    unsigned u2 = __float_as_uint(lf);
    unsigned r2 = (u2 + 0x7fffu + ((u2 >> 16) & 1u)) >> 16;
    lo = (short)r2;
}

// Tile-major pack. Output: chunk c = (g*16 + part*8 + kc), each chunk
// 128 rows x 32 shorts (8 KB contiguous). Within a row, slot s (8 shorts)
// holds k-octet (swz ? s^((r>>1)&3) : s) of k-range [kc*32, kc*32+32).
// swz=1: LDS bank-swizzle baked into global layout (A path, R2-verbatim,
// rule #21: global_load_lds stages linearly on BOTH sides, ds_read applies
// the XOR). swz=0: plain row-major (B path, direct global->reg fragment
// reads — a wave's 64 lanes cover one contiguous 1 KB span per fragment).
__global__ void pack_tiles_kernel(const float* __restrict__ src,
                                  unsigned short* __restrict__ dst,
                                  int total, int swz) {   // total = rows * 32
    int tid = blockIdx.x * blockDim.x + threadIdx.x;
    if (tid >= total) return;
    int s   = tid & 3;
    int r   = (tid >> 2) & 127;
    int kc  = (tid >> 9) & 7;
    int g   = tid >> 12;
    int oct = swz ? (s ^ ((r >> 1) & 3)) : s;

    const float4* xr = reinterpret_cast<const float4*>(
        src + ((size_t)(g * 128 + r)) * DIM + kc * 32 + oct * 8);
    float4 v0 = xr[0];
    float4 v1 = xr[1];

    float f[8] = {v0.x, v0.y, v0.z, v0.w, v1.x, v1.y, v1.z, v1.w};
    s16x8 hv, lv;
#pragma unroll
    for (int i = 0; i < 8; ++i) {
        short h, l;
        f2bf_split(f[i], h, l);
        hv[i] = h; lv[i] = l;
    }
    size_t base_hi = (((size_t)(g * 16 + kc) * 128 + r) << 5) + s * 8;
    size_t base_lo = (((size_t)(g * 16 + 8 + kc) * 128 + r) << 5) + s * 8;
    *reinterpret_cast<s16x8*>(dst + base_hi) = hv;
    *reinterpret_cast<s16x8*>(dst + base_lo) = lv;
}

// Async global -> LDS, 16 B per lane; LDS dest = uniform base + lane*16.
__device__ __forceinline__ void gload_lds16(const unsigned short* g, unsigned short* lds) {
    __builtin_amdgcn_global_load_lds(
        (const __attribute__((address_space(1))) unsigned int*)g,
        (__attribute__((address_space(3))) unsigned int*)lds, 16, 0, 0);
}

// MFMA distance + top-2. dist' = c_sq - 2*(x.c); ||x||^2 dropped (cancels).
// dot = hi*hi + hi*lo + lo*hi as one K=768 concat-GEMM over 3 segments.
//
// R8: PIPE-SPLIT. Per-pipe arithmetic across R0-R7 (32-CU partition model):
// every variant pushed ALL operand traffic through one pipe — R2: 147 MB/CU
// through LDS (~650-720 us-equiv, matches measured); R4: 98 MB/CU through
// VMEM (~680, matches). Here A keeps R2's proven LDS staging (LDS traffic
// halves to ~74 MB/CU) while B-fragments are read DIRECTLY global->reg from
// the L2-resident 1-MB unswizzled cb pack (VMEM ~74 MB/CU). Two pipes at
// ~350/~480 us-equiv instead of one at ~720; MFMA floor ~400. B values and
// per-acc accumulation order identical to R2 -> bit-exact.
__launch_bounds__(NTHREADS, 4)
__global__ void vq_main_kernel(const unsigned short* __restrict__ xpk,
                               const unsigned short* __restrict__ cbpk,
                               const float* __restrict__ csq,
                               float4* __restrict__ pairs) {
    // A tiles only: 2 x 128x32 shorts = 16 KB, + 4 KB epilogue = 20 KB
    __shared__ __align__(16) unsigned short shbuf[2][TM * BK];
    __shared__ float4 pairs_sh[TM][2];

    const int tid  = threadIdx.x;
    const int w    = tid >> 6;       // wave 0..3
    const int wy   = w >> 1;         // wave row (token dim)
    const int wx   = w & 1;          // wave col (code dim)
    const int lane = tid & 63;
    const int lm   = lane & 15;
    const int q    = lane >> 4;

    // XCD-grouped swizzle (bijective): the 8 sibling chunk-blocks of one
    // token group are adjacent in dispatch -> x slabs L2-shared.
    const int bx     = blockIdx.x;
    const int jj     = bx >> 3;
    const int grp    = (bx & 7) + ((jj >> 3) << 3);
    const int cchunk = jj & 7;
    const int tok0   = grp * TM;
    const int code0  = cchunk * TN;

    float cs_reg[4];
#pragma unroll
    for (int ni = 0; ni < 4; ++ni)
        cs_reg[ni] = csq[code0 + wx * 64 + ni * 16 + lm];

    f32x4 acc[4][4];
#pragma unroll
    for (int mi = 0; mi < 4; ++mi)
#pragma unroll
        for (int ni = 0; ni < 4; ++ni)
            acc[mi][ni] = (f32x4){0.f, 0.f, 0.f, 0.f};

    // A fragment LDS offsets (shorts): row r, k-octet q at swizzled slot
    // (q ^ ((r>>1)&3)) — R2 verbatim.
    int offA[4];
#pragma unroll
    for (int mi = 0; mi < 4; ++mi) {
        int r = wy * 64 + mi * 16 + lm;
        offA[mi] = r * BK + ((q ^ ((r >> 1) & 3)) * 8);
    }
    // B fragment per-lane global offsets (shorts) within a chunk:
    // row rB = wx*64+ni*16+lm, octet q at UNswizzled slot q. A wave's 64
    // lanes cover rows [.,.+16) x 64 B = one contiguous 1 KB span.
    int offB[4];
#pragma unroll
    for (int ni = 0; ni < 4; ++ni) {
        int r = wx * 64 + ni * 16 + lm;
        offB[ni] = r * BK + q * 8;
    }

    // stage s (0..23): seg = s>>3, kc = s&7. A part: hi,hi,lo (pa).
    const int lsrc = w * 1024 + lane * 8;   // per-lane source offset (shorts)
    auto stage = [&](int p, int s) {
        const int kc = s & 7;
        const int pa = (s >= 16) ? 8 : 0;
        const unsigned short* ga = xpk + (((size_t)(grp * 16 + pa + kc)) << 12) + lsrc;
        unsigned short* At = &shbuf[p][w * 1024];
        gload_lds16(ga,       At);
        gload_lds16(ga + 512, At + 512);
    };

    // Prologue: fill buffer 0 with stage 0, drain.
    stage(0, 0);
    __syncthreads();

    int p = 0;
#pragma unroll 1
    for (int s = 0; s < NSTAGE; ++s) {
        // B for THIS stage: direct global->reg (L2-resident, coalesced 1KB
        // per fragment). Issued first so the ~200-cyc L2 latency hides
        // under the A prefetch issue + ds_reads below. B part: hi,lo,hi.
        const int kc = s & 7;
        const int pb = (s >= 8 && s < 16) ? 8 : 0;
        const unsigned short* gb =
            cbpk + (((size_t)(cchunk * 16 + pb + kc)) << 12);
        bf16x8 bf[4];
#pragma unroll
        for (int ni = 0; ni < 4; ++ni)
            bf[ni] = *reinterpret_cast<const bf16x8*>(gb + offB[ni]);

        if (s < NSTAGE - 1) stage(p ^ 1, s + 1);   // A prefetch (async LDS)

        const unsigned short* buf = &shbuf[p][0];
        bf16x8 af[4];
#pragma unroll
        for (int mi = 0; mi < 4; ++mi)
            af[mi] = *reinterpret_cast<const bf16x8*>(buf + offA[mi]);

        __builtin_amdgcn_s_setprio(1);
#pragma unroll
        for (int mi = 0; mi < 4; ++mi)
#pragma unroll
            for (int ni = 0; ni < 4; ++ni)
                acc[mi][ni] = __builtin_amdgcn_mfma_f32_16x16x32_bf16(
                    af[mi], bf[ni], acc[mi][ni], 0, 0, 0);
        __builtin_amdgcn_s_setprio(0);

        __syncthreads();   // drains vmcnt (A prefetch landed) + lgkm
        p ^= 1;
    }

    // Extraction: C/D layout row=(q*4+reg), col=lm per 16x16 tile (verified R6).
#pragma unroll
    for (int mi = 0; mi < 4; ++mi) {
#pragma unroll
        for (int r = 0; r < 4; ++r) {
            int row_local = wy * 64 + mi * 16 + q * 4 + r;
            float l1 = 3.4e38f, l2 = 3.4e38f;
            int   j1 = 0x7fffffff, j2 = 0x7fffffff;
#pragma unroll
            for (int ni = 0; ni < 4; ++ni) {
                float d = cs_reg[ni] - 2.0f * acc[mi][ni][r];
                ins2(d, code0 + wx * 64 + ni * 16 + lm, l1, j1, l2, j2);
            }
#pragma unroll
            for (int m = 1; m < 16; m <<= 1) {
                float o1 = __shfl_xor(l1, m);
                int   p1 = __shfl_xor(j1, m);
                float o2 = __shfl_xor(l2, m);
                int   p2 = __shfl_xor(j2, m);
                ins2(o1, p1, l1, j1, l2, j2);
                ins2(o2, p2, l1, j1, l2, j2);
            }
            if (lm == 0) {
                float4 pr;
                pr.x = l1; pr.y = l2;
                pr.z = __int_as_float(j1); pr.w = __int_as_float(j2);
                pairs_sh[row_local][wx] = pr;
            }
        }
    }
    __syncthreads();
    if (tid < TM) {
        float4 pa = pairs_sh[tid][0];
        float4 pb = pairs_sh[tid][1];
        float d1 = pa.x, d2 = pa.y;
        int   i1 = __float_as_int(pa.z), i2 = __float_as_int(pa.w);
        ins2(pb.x, __float_as_int(pb.z), d1, i1, d2, i2);
        ins2(pb.y, __float_as_int(pb.w), d1, i1, d2, i2);
        float4 pr;
        pr.x = d1; pr.y = d2;
        pr.z = __int_as_float(i1); pr.w = __int_as_float(i2);
        // chunk-major: contiguous 16B stores across tid
        pairs[(size_t)cchunk * N_TOK + tok0 + tid] = pr;
    }
}

// Fused merge + refine + output. Phase 1: 128 threads merge the 8 chunk
// top-2 pairs (ascending chunk order) and fp64-refine near-ties. Phase 2:
// all 256 threads write quantized rows + indices + loss partials.
__launch_bounds__(256)
__global__ void merge_output_kernel(const float* __restrict__ x,
                                    const float* __restrict__ cb,
                                    const float4* __restrict__ pairs,
                                    float* __restrict__ out_q,
                                    float* __restrict__ out_idx,
                                    float* __restrict__ loss_ws) {
    __shared__ int   sh_idx[OTM];
    __shared__ float wsum[4];
    const int tid  = threadIdx.x;
    const int tok0 = blockIdx.x * OTM;

    if (tid < OTM) {
        const int t = tok0 + tid;
        float4 p0 = pairs[t];
        float d1 = p0.x, d2 = p0.y;
        int   i1 = __float_as_int(p0.z), i2 = __float_as_int(p0.w);
#pragma unroll
        for (int c = 1; c < NCHUNK; ++c) {
            float4 p = pairs[(size_t)c * N_TOK + t];
            ins2(p.x, __float_as_int(p.z), d1, i1, d2, i2);
            ins2(p.y, __float_as_int(p.w), d1, i1, d2, i2);
        }

        int pick = i1;
        if (d2 - d1 < REFINE_EPS) {
            const float* xr = x + (size_t)t * DIM;
            const float* c1 = cb + (size_t)i1 * DIM;
            const float* c2 = cb + (size_t)i2 * DIM;
            double sA = 0.0, dA = 0.0, sB = 0.0, dB = 0.0;
            for (int k = 0; k < DIM; ++k) {
                double xv = (double)xr[k];
                double a  = (double)c1[k];
                double b  = (double)c2[k];
                sA += a * a; dA += xv * a;
                sB += b * b; dB += xv * b;
            }
            double DA  = sA - 2.0 * dA;
            double DB  = sB - 2.0 * dB;
            double gap = DB - DA;
            if (gap > TIE_THETA)       pick = i1;
            else if (gap < -TIE_THETA) pick = i2;
            else                       pick = (i1 < i2) ? i1 : i2;
        }
        sh_idx[tid] = pick;
        out_idx[t]  = (float)pick;
    }
    __syncthreads();

    float lsum = 0.0f;
    for (int t = 0; t < OTM; ++t) {
        int code = sh_idx[t];
        float qv = cb[(size_t)code * DIM + tid];
        float xv = x[(size_t)(tok0 + t) * DIM + tid];
        out_q[(size_t)(tok0 + t) * DIM + tid] = xv + (qv - xv);
        float df = xv - qv;
        lsum = fmaf(df, df, lsum);
    }

#pragma unroll
    for (int off = 1; off < 64; off <<= 1) lsum += __shfl_xor(lsum, off);
    if ((tid & 63) == 0) wsum[tid >> 6] = lsum;
    __syncthreads();
    if (tid == 0) atomicAdd(loss_ws, (wsum[0] + wsum[1]) + (wsum[2] + wsum[3]));
}

__global__ void finalize_kernel(const float* ws, float* out_loss) {
    if (threadIdx.x == 0) out_loss[0] = ws[0] * (1.0f / 16777216.0f); // COMMITMENT * mean
}

extern "C" void kernel_launch(void* const* d_in, const int* in_sizes, int n_in,
                              void* d_out, int out_size, void* d_ws, size_t ws_size,
                              hipStream_t stream) {
    const float* x  = (const float*)d_in[0];   // [16,4096,256] fp32
    const float* cb = (const float*)d_in[1];   // [1024,256] fp32

    float* out      = (float*)d_out;
    float* out_q    = out;
    float* out_idx  = out + (size_t)N_TOK * DIM;
    float* out_loss = out_idx + N_TOK;

    float*  ws    = (float*)d_ws;
    float*  csq   = ws + WS_CSQ_OFF;
    float4* pairs = (float4*)(ws + WS_PAIRS_OFF);
    unsigned short* cbpk = (unsigned short*)(ws + WS_CBPK_OFF);
    // x packed bf16 hi/lo lives in the out_q region (64 MB, overwritten later)
    unsigned short* xpk  = (unsigned short*)out_q;

    rowsq_np_kernel<<<KCODE / 16, 256, 0, stream>>>(cb, csq, ws, KCODE);
    // x: swizzled pack (LDS staging path); cb: UNswizzled (direct B reads)
    pack_tiles_kernel<<<(N_TOK * 32) / 256, 256, 0, stream>>>(x, xpk, N_TOK * 32, 1);
    pack_tiles_kernel<<<(KCODE * 32) / 256, 256, 0, stream>>>(cb, cbpk, KCODE * 32, 0);
    vq_main_kernel<<<(N_TOK / TM) * NCHUNK, NTHREADS, 0, stream>>>(xpk, cbpk, csq, pairs);
    merge_output_kernel<<<N_TOK / OTM, 256, 0, stream>>>(x, cb, pairs, out_q, out_idx, ws);
    finalize_kernel<<<1, 64, 0, stream>>>(ws, out_loss);
}